// Round 5
// baseline (208.039 us; speedup 1.0000x reference)
//
#include <hip/hip_runtime.h>

// Yoshida 4th-order integrator, Gamma(v) = W @ (U v)^2, B=4096, D=1024, R=256.
// Fused 3-step kernel, fp8 e4m3 MFMA path (validated R4). R4 finding: nothing
// saturated (L2 7.9/34.5 TB/s, HBM 18%, Mfma 9%, VALU 9%) -> latency/barrier
// bound: 16 lockstep waves/CU stall together at 6 __syncthreads. This round:
// M=8 rows/block, grid=512 -> 2 independent blocks/CU, 32 waves/CU (full
// occupancy), barriers decorrelated. A-tile rows 8..15 zeroed (zero A-rows
// only affect output rows 8..15, never stored). Aggregate L2 stream doubles
// to 768MB (~25 TB/s at target 30us, still under 34.5 ceiling) -- deliberate
// trade of bytes for TLP.

#define BSZ 4096
#define DD 1024
#define RR 256
#define MROWS 8

typedef unsigned char uchar;
typedef long long i64;
typedef __attribute__((ext_vector_type(2))) long i64x2;
typedef __attribute__((ext_vector_type(4))) float f32x4;
typedef __attribute__((ext_vector_type(4))) unsigned int uint4v;

// pack 4 floats -> 4 fp8 e4m3 bytes (HW cvt, RNE, saturating)
__device__ inline unsigned int f2q4(float a, float b, float c, float d) {
    int lo = __builtin_amdgcn_cvt_pk_fp8_f32(a, b, 0, false);
    int hi = __builtin_amdgcn_cvt_pk_fp8_f32(c, d, lo, true);
    return (unsigned int)hi;
}
__device__ inline uchar f2q1(float x) {
    return (uchar)(__builtin_amdgcn_cvt_pk_fp8_f32(x, x, 0, false) & 0xff);
}

// ---- pack U [R,D] (x8) and W [D,R] (x16) into fragment-major fp8 -----------
// Fragment pair layout: lane l holds 16 bytes = kt=2p (k=kb..kb+7) then
// kt=2p+1 (k=kb+32..kb+39), kb = p*64 + (l>>4)*8; n = tile*16 + (l&15).
__global__ __launch_bounds__(256) void pack_uw_kernel(
    const float* __restrict__ U, const float* __restrict__ W,
    uchar* __restrict__ Upk, uchar* __restrict__ Wpk)
{
    const int g = blockIdx.x * 256 + threadIdx.x;
    const float* src;
    uchar* dst;
    float sc;
    if (g < 16384) {                       // U: 16 nt x 16 p x 64 l
        const int l = g & 63, p = (g >> 6) & 15, nt = g >> 10;
        src = U + (size_t)(nt * 16 + (l & 15)) * DD + p * 64 + (l >> 4) * 8;
        dst = Upk + ((size_t)nt << 14) + (p << 10) + (l << 4);
        sc = 8.0f;
    } else {                               // W: 64 dtile x 4 p x 64 l
        const int g2 = g - 16384;
        const int l = g2 & 63, p = (g2 >> 6) & 3, dt_ = g2 >> 8;
        src = W + (size_t)(dt_ * 16 + (l & 15)) * RR + p * 64 + (l >> 4) * 8;
        dst = Wpk + ((size_t)dt_ << 12) + (p << 10) + (l << 4);
        sc = 16.0f;
    }
    const float4 x0 = *reinterpret_cast<const float4*>(src);
    const float4 x1 = *reinterpret_cast<const float4*>(src + 4);
    const float4 y0 = *reinterpret_cast<const float4*>(src + 32);
    const float4 y1 = *reinterpret_cast<const float4*>(src + 36);
    uint4v o;
    o.x = f2q4(sc * x0.x, sc * x0.y, sc * x0.z, sc * x0.w);
    o.y = f2q4(sc * x1.x, sc * x1.y, sc * x1.z, sc * x1.w);
    o.z = f2q4(sc * y0.x, sc * y0.y, sc * y0.z, sc * y0.w);
    o.w = f2q4(sc * y1.x, sc * y1.y, sc * y1.z, sc * y1.w);
    *reinterpret_cast<uint4v*>(dst) = o;
}

// ---- fused 3-step integrator ----------------------------------------------
__global__ __launch_bounds__(1024, 8) void yoshida_fused_kernel(
    const float* __restrict__ x_in,
    const float* __restrict__ v_in,
    const float* __restrict__ force,
    const uchar* __restrict__ Upk,
    const uchar* __restrict__ Wpk,
    float* __restrict__ x_out,
    float* __restrict__ v_out)
{
    // byte pitches 1040 / 272 (260 / 68 words, %32==4) -> near-conflict-free
    __shared__ __align__(16) uchar vS[16][1040];
    __shared__ __align__(16) uchar H2S[16][272];

    const int tid = threadIdx.x;
    const int w = tid >> 6, l = tid & 63;
    const int m = l & 15, q = l >> 4;
    const int b0 = blockIdx.x * MROWS;
    const int d0 = w * 64;
    const bool rowlane = (q < 2);   // lanes owning valid rows 0..7 (r = q*4+i)

    constexpr double CBRT2 = 1.2599210498948731647672106072782;
    constexpr double W1c = 1.0 / (2.0 - CBRT2);
    constexpr double W0c = -CBRT2 * W1c;
    constexpr double DTd = 0.01 * 1.0;
    const float dcoef[3] = {(float)(W1c * DTd), (float)(W0c * DTd), (float)(W1c * DTd)};
    const float xcoef[3] = {(float)((W0c + W1c) * 0.5), (float)((W0c + W1c) * 0.5),
                            (float)(W1c * 0.5)};
    const float c1  = (float)(W1c * 0.5);
    const float dtf = (float)DTd;

    // --- per-lane fp32 state + force in registers (C/D layout, rows 0..7) ---
    float vreg[16], xacc[16], freg[16];
    if (rowlane) {
        #pragma unroll
        for (int t = 0; t < 4; ++t)
            #pragma unroll
            for (int i = 0; i < 4; ++i) {
                const size_t gidx = (size_t)(b0 + q * 4 + i) * DD + d0 + t * 16 + m;
                const float vv = v_in[gidx];
                vreg[t * 4 + i] = vv;
                xacc[t * 4 + i] = c1 * vv;
                freg[t * 4 + i] = force[gidx];
            }
    }

    // --- stage v rows 0..7 into LDS as fp8; zero rows 8..15 -----------------
    {
        const int row = tid >> 6;          // 0..15
        const int col = (tid & 63) * 16;
        if (row < MROWS) {
            const float* sp = v_in + (size_t)(b0 + row) * DD + col;
            const float4 f0 = *reinterpret_cast<const float4*>(sp);
            const float4 f1 = *reinterpret_cast<const float4*>(sp + 4);
            const float4 f2 = *reinterpret_cast<const float4*>(sp + 8);
            const float4 f3 = *reinterpret_cast<const float4*>(sp + 12);
            uint4v pk;
            pk.x = f2q4(f0.x, f0.y, f0.z, f0.w);
            pk.y = f2q4(f1.x, f1.y, f1.z, f1.w);
            pk.z = f2q4(f2.x, f2.y, f2.z, f2.w);
            pk.w = f2q4(f3.x, f3.y, f3.z, f3.w);
            *reinterpret_cast<uint4v*>(&vS[row][col]) = pk;
        } else {
            *reinterpret_cast<uint4v*>(&vS[row][col]) = (uint4v){0, 0, 0, 0};
        }
    }

    const uchar* up = Upk + ((size_t)w << 14) + (l << 4);       // wave's 16KB U
    const uchar* wp = Wpk + ((size_t)(w * 4) << 12) + (l << 4); // wave's 16KB W

    #pragma unroll
    for (int s = 0; s < 3; ++s) {
        __syncthreads();   // s==0: vS staged; s>0: epilogue vS writes visible

        // ---- GEMM A: accA = (8U) . v_q, K=1024, 2 independent chains --------
        f32x4 a0 = {0.f, 0.f, 0.f, 0.f}, a1 = {0.f, 0.f, 0.f, 0.f};
        #pragma unroll
        for (int p = 0; p < 16; ++p) {
            const i64x2 bb = *reinterpret_cast<const i64x2*>(up + (p << 10));
            const i64 af0 = *reinterpret_cast<const i64*>(&vS[m][p * 64 + q * 8]);
            const i64 af1 = *reinterpret_cast<const i64*>(&vS[m][p * 64 + 32 + q * 8]);
            a0 = __builtin_amdgcn_mfma_f32_16x16x32_fp8_fp8(af0, bb.x, a0, 0, 0, 0);
            a1 = __builtin_amdgcn_mfma_f32_16x16x32_fp8_fp8(af1, bb.y, a1, 0, 0, 0);
        }
        #pragma unroll
        for (int i = 0; i < 4; ++i) {
            const float h8 = a0[i] + a1[i];                    // = 8*h (rows>=8: 0)
            H2S[q * 4 + i][w * 16 + m] = f2q1(h8 * h8 * 0.015625f);  // h^2
        }
        __syncthreads();   // H2S published

        // ---- GEMM B: accB = (16W) . h2_q, K=256 -----------------------------
        f32x4 accB[4];
        #pragma unroll
        for (int t = 0; t < 4; ++t) accB[t] = (f32x4){0.f, 0.f, 0.f, 0.f};
        #pragma unroll
        for (int p = 0; p < 4; ++p) {
            const i64 ha0 = *reinterpret_cast<const i64*>(&H2S[m][p * 64 + q * 8]);
            const i64 ha1 = *reinterpret_cast<const i64*>(&H2S[m][p * 64 + 32 + q * 8]);
            #pragma unroll
            for (int t = 0; t < 4; ++t) {
                const i64x2 wb = *reinterpret_cast<const i64x2*>(wp + (t << 12) + (p << 10));
                accB[t] = __builtin_amdgcn_mfma_f32_16x16x32_fp8_fp8(ha0, wb.x, accB[t], 0, 0, 0);
                accB[t] = __builtin_amdgcn_mfma_f32_16x16x32_fp8_fp8(ha1, wb.y, accB[t], 0, 0, 0);
            }
        }

        // ---- epilogue (rows 0..7 lanes): v update; vS <- fp8(v) -------------
        const float ddt = dcoef[s], cx = xcoef[s], gsc = dcoef[s] * 0.0625f;
        if (rowlane) {
            #pragma unroll
            for (int t = 0; t < 4; ++t)
                #pragma unroll
                for (int i = 0; i < 4; ++i) {
                    const float vn = vreg[t * 4 + i] + ddt * freg[t * 4 + i]
                                     - gsc * accB[t][i];
                    vreg[t * 4 + i] = vn;
                    xacc[t * 4 + i] += cx * vn;
                    vS[q * 4 + i][d0 + t * 16 + m] = f2q1(vn);
                }
        }
    }

    // ---- final stores (rows 0..7): x = x_in + dt*xacc; v = vreg -------------
    if (rowlane) {
        #pragma unroll
        for (int t = 0; t < 4; ++t)
            #pragma unroll
            for (int i = 0; i < 4; ++i) {
                const size_t g = (size_t)(b0 + q * 4 + i) * DD + d0 + t * 16 + m;
                x_out[g] = x_in[g] + dtf * xacc[t * 4 + i];
                v_out[g] = vreg[t * 4 + i];
            }
    }
}

extern "C" void kernel_launch(void* const* d_in, const int* in_sizes, int n_in,
                              void* d_out, int out_size, void* d_ws, size_t ws_size,
                              hipStream_t stream) {
    const float* x     = (const float*)d_in[0];
    const float* v     = (const float*)d_in[1];
    const float* force = (const float*)d_in[2];
    const float* U     = (const float*)d_in[3];
    const float* W     = (const float*)d_in[4];

    float* x_out = (float*)d_out;
    float* v_out = x_out + (size_t)BSZ * DD;

    uchar* Upk = (uchar*)d_ws;                 // 256 KB
    uchar* Wpk = Upk + (size_t)RR * DD;        // 256 KB

    pack_uw_kernel<<<dim3(128), dim3(256), 0, stream>>>(U, W, Upk, Wpk);
    yoshida_fused_kernel<<<dim3(BSZ / MROWS), dim3(1024), 0, stream>>>(
        x, v, force, Upk, Wpk, x_out, v_out);
}